// Round 7
// baseline (233.979 us; speedup 1.0000x reference)
//
#include <hip/hip_runtime.h>

#define N_NODES 50000
#define N_EDGES 200000
#define S_DIM   8
#define F_DIM   32      // F_IN == F == 32
#define G_SEG   512
#define P_PAIRS 1024
#define A_COLS  288     // 9*32 : 8 Wk rows + 1 bk row
#define NB      16      // source nodes per fused block
#define N2      (2 * N_NODES)
#define SCAN_B2 391     // ceil(2*N_NODES/256)
#define SCAN_B  196     // ceil(N_NODES/256)

// ---------------------------------------------------------------------------
// K0: zero combined degree array (src+tgt) and pooled[]
// ---------------------------------------------------------------------------
__global__ __launch_bounds__(256)
void zero_init(int* __restrict__ deg2, float* __restrict__ pooled)
{
    const int gid = blockIdx.x * 256 + threadIdx.x;
    if (gid < N2) deg2[gid] = 0;
    if (gid < G_SEG * F_DIM) pooled[gid] = 0.f;
}

// combined histogram: deg2[0..N) = out-degree by src, deg2[N..2N) = in-degree by tgt
__global__ __launch_bounds__(256)
void deg_hist(const int* __restrict__ src, const int* __restrict__ tgt,
              int* __restrict__ deg2)
{
    const int e = blockIdx.x * 256 + threadIdx.x;
    if (e < N_EDGES) {
        atomicAdd(&deg2[src[e]], 1);
        atomicAdd(&deg2[N_NODES + tgt[e]], 1);
    }
}

__global__ __launch_bounds__(256)
void sum_blocks(const int* __restrict__ deg2, int* __restrict__ partial)
{
    __shared__ int sd[256];
    const int t = threadIdx.x;
    const int n = blockIdx.x * 256 + t;
    sd[t] = (n < N2) ? deg2[n] : 0;
    __syncthreads();
    for (int off = 128; off > 0; off >>= 1) {
        if (t < off) sd[t] += sd[t + off];
        __syncthreads();
    }
    if (t == 0) partial[blockIdx.x] = sd[0];
}

// single-block exclusive scan of SCAN_B2 partials (512 threads)
__global__ __launch_bounds__(512)
void scan_partials(const int* __restrict__ partial, int* __restrict__ blockoff)
{
    __shared__ int sd[512];
    const int t = threadIdx.x;
    sd[t] = (t < SCAN_B2) ? partial[t] : 0;
    __syncthreads();
    for (int off = 1; off < 512; off <<= 1) {
        int v = (t >= off) ? sd[t - off] : 0;
        __syncthreads();
        sd[t] += v;
        __syncthreads();
    }
    if (t < SCAN_B2) blockoff[t] = (t == 0) ? 0 : sd[t - 1];
}

// combined rowstart: row[0..N) = src CSR starts; row[N..2N) = E + tgt CSR starts
__global__ __launch_bounds__(256)
void write_rowstart(const int* __restrict__ deg2, const int* __restrict__ blockoff,
                    int* __restrict__ row, int* __restrict__ cursor)
{
    __shared__ int sd[256];
    const int t = threadIdx.x;
    const int n = blockIdx.x * 256 + t;
    const int d = (n < N2) ? deg2[n] : 0;
    sd[t] = d;
    __syncthreads();
    for (int off = 1; off < 256; off <<= 1) {
        int v = (t >= off) ? sd[t - off] : 0;
        __syncthreads();
        sd[t] += v;
        __syncthreads();
    }
    if (n < N2) {
        const int rs = blockoff[blockIdx.x] + sd[t] - d;
        row[n]    = rs;
        cursor[n] = rs;
    }
    if (blockIdx.x == 0 && t == 0) row[N2] = 2 * N_EDGES;
}

// scatter edges into src-sorted order; assign tgt-sorted slot; pre-gather evec
__global__ __launch_bounds__(256)
void csr_scatter(const int* __restrict__ src, const int* __restrict__ tgt,
                 const float* __restrict__ evec, int* __restrict__ cursor,
                 int* __restrict__ srcs, int* __restrict__ postgt,
                 float* __restrict__ esort)
{
    const int e = blockIdx.x * 256 + threadIdx.x;
    if (e < N_EDGES) {
        const int sn  = src[e];
        const int tn  = tgt[e];
        const int pos  = atomicAdd(&cursor[sn], 1);
        const int post = atomicAdd(&cursor[N_NODES + tn], 1) - N_EDGES;
        srcs[pos]   = sn;
        postgt[pos] = post;
        const float4* s4 = (const float4*)(evec + (size_t)e * S_DIM);
        float4* d4 = (float4*)(esort + (size_t)pos * S_DIM);
        d4[0] = s4[0];
        d4[1] = s4[1];
    }
}

// ---------------------------------------------------------------------------
// agg_init: agg[n][o] = b[o] + sum_i h[n][i] * root[i][o]
// ---------------------------------------------------------------------------
template <int LAYER>
__global__ __launch_bounds__(256)
void agg_init(const float* __restrict__ hsrc, const float* __restrict__ root,
              const float* __restrict__ bias, float* __restrict__ agg)
{
    __shared__ float r[F_DIM * F_DIM];
    __shared__ float bsh[F_DIM];
    for (int t = threadIdx.x; t < F_DIM * F_DIM; t += 256) r[t] = root[t];
    if (threadIdx.x < F_DIM) bsh[threadIdx.x] = bias[threadIdx.x];
    __syncthreads();

    const int gid = blockIdx.x * 256 + threadIdx.x;
    if (gid >= N_NODES * F_DIM) return;
    const int n = gid >> 5, o = gid & 31;

    float acc = bsh[o];
    #pragma unroll
    for (int i = 0; i < F_DIM; ++i) {
        float h;
        if (LAYER == 0) h = hsrc[(size_t)n * (F_DIM + 1) + i];
        else {
            h = hsrc[(size_t)n * F_DIM + i];
            h = h > 0.f ? h : 0.f;
        }
        acc += h * r[i * F_DIM + o];
    }
    agg[gid] = acc;
}

// ---------------------------------------------------------------------------
// fused_ecc: per block of NB=16 source nodes:
//   phase 1: A-tile[16][288] in LDS
//   phase 2: per src-sorted edge, compute msg and STORE (no atomic!) into
//            msgbuf at its tgt-sorted slot: one full 128B line per edge.
// ---------------------------------------------------------------------------
template <int LAYER>
__global__ __launch_bounds__(320)
void fused_ecc(const float* __restrict__ hsrc,
               const float* __restrict__ Wk, const float* __restrict__ bk,
               const int* __restrict__ row, const int* __restrict__ srcs,
               const int* __restrict__ postgt, const float* __restrict__ esort,
               float* __restrict__ msgbuf)
{
    __shared__ float hh[NB][F_DIM];
    __shared__ float At[NB][A_COLS];

    const int nb   = blockIdx.x * NB;
    const int nmax = (N_NODES - nb < NB) ? (N_NODES - nb) : NB;

    if (LAYER == 0) {
        for (int idx = threadIdx.x; idx < nmax * F_DIM; idx += 320) {
            const int n = idx >> 5, i = idx & 31;
            hh[n][i] = hsrc[(size_t)(nb + n) * (F_DIM + 1) + i];
        }
    } else {
        const float4* s4 = (const float4*)(hsrc + (size_t)nb * F_DIM);
        for (int idx = threadIdx.x; idx < nmax * (F_DIM / 4); idx += 320) {
            float4 v = s4[idx];
            v.x = v.x > 0.f ? v.x : 0.f;
            v.y = v.y > 0.f ? v.y : 0.f;
            v.z = v.z > 0.f ? v.z : 0.f;
            v.w = v.w > 0.f ? v.w : 0.f;
            ((float4*)hh)[idx] = v;
        }
    }
    __syncthreads();

    const int c = threadIdx.x;
    if (c < A_COLS) {
        float w[F_DIM];
        const int o = c & 31;
        if (c < 256) {
            const int s = c >> 5;
            #pragma unroll
            for (int i = 0; i < F_DIM; ++i) w[i] = Wk[s * (F_DIM * F_DIM) + i * F_DIM + o];
        } else {
            #pragma unroll
            for (int i = 0; i < F_DIM; ++i) w[i] = bk[i * F_DIM + o];
        }
        for (int n = 0; n < nmax; ++n) {
            const float4* hv = (const float4*)hh[n];
            float acc = 0.f;
            #pragma unroll
            for (int i4 = 0; i4 < F_DIM / 4; ++i4) {
                float4 h4 = hv[i4];
                acc += h4.x * w[4*i4]   + h4.y * w[4*i4+1]
                     + h4.z * w[4*i4+2] + h4.w * w[4*i4+3];
            }
            At[n][c] = acc;
        }
    }
    __syncthreads();

    const int r0 = row[nb];
    const int r1 = row[nb + nmax];
    const int nwork = (r1 - r0) * F_DIM;
    for (int idx = threadIdx.x; idx < nwork; idx += 320) {
        const int pos = r0 + (idx >> 5);
        const int o   = idx & 31;
        const int ls  = srcs[pos] - nb;
        const int pt  = postgt[pos];
        const float4* ev4 = (const float4*)(esort + (size_t)pos * S_DIM);
        const float4 e0 = ev4[0];
        const float4 e1 = ev4[1];
        const float* Ar = At[ls];
        float m = Ar[8 * F_DIM + o];          // bk row (implicit e'_8 = 1)
        m += e0.x * Ar[0 * F_DIM + o];
        m += e0.y * Ar[1 * F_DIM + o];
        m += e0.z * Ar[2 * F_DIM + o];
        m += e0.w * Ar[3 * F_DIM + o];
        m += e1.x * Ar[4 * F_DIM + o];
        m += e1.y * Ar[5 * F_DIM + o];
        m += e1.z * Ar[6 * F_DIM + o];
        m += e1.w * Ar[7 * F_DIM + o];
        msgbuf[(size_t)pt * F_DIM + o] = m;   // plain full-line store
    }
}

// ---------------------------------------------------------------------------
// seg_reduce: agg[t][o] += sum over this target's contiguous msg rows.
// Thread (tloc,o) owns one (target, column); rows are tgt-CSR contiguous.
// ---------------------------------------------------------------------------
__global__ __launch_bounds__(256)
void seg_reduce(const float* __restrict__ msgbuf, const int* __restrict__ row,
                float* __restrict__ agg)
{
    const int o    = threadIdx.x & 31;
    const int tloc = threadIdx.x >> 5;                 // 0..7
    const int t    = blockIdx.x * 8 + tloc;
    if (t >= N_NODES) return;

    const int r0 = row[N_NODES + t] - N_EDGES;
    const int r1 = row[N_NODES + t + 1] - N_EDGES;

    float acc = agg[(size_t)t * F_DIM + o];
    for (int r = r0; r < r1; ++r)
        acc += msgbuf[(size_t)r * F_DIM + o];
    agg[(size_t)t * F_DIM + o] = acc;
}

// ---------------------------------------------------------------------------
// pool: pooled[seg[n]] += trunc(relu(agg2[n])). seg sorted -> run-based.
// ---------------------------------------------------------------------------
__global__ __launch_bounds__(256)
void pool_kernel(const float* __restrict__ agg2, const int* __restrict__ seg,
                 float* __restrict__ pooled)
{
    const int o    = threadIdx.x & 31;
    const int r    = threadIdx.x >> 5;
    const int base = blockIdx.x * 256 + r * 32;

    int   curseg = -1;
    float acc    = 0.f;
    for (int i = 0; i < 32; ++i) {
        const int n = base + i;
        if (n >= N_NODES) break;
        const int sg = seg[n];
        if (sg != curseg) {
            if (curseg >= 0 && acc != 0.f)
                atomicAdd(&pooled[(size_t)curseg * F_DIM + o], acc);
            curseg = sg;
            acc = 0.f;
        }
        float v = agg2[(size_t)n * F_DIM + o];
        v = v > 0.f ? v : 0.f;
        acc += truncf(v);
    }
    if (curseg >= 0 && acc != 0.f)
        atomicAdd(&pooled[(size_t)curseg * F_DIM + o], acc);
}

// ---------------------------------------------------------------------------
// head: out[g] = relu(pooled[g].Wd + bd); result[p] = out[ib[p]] - out[ia[p]]
// ---------------------------------------------------------------------------
__global__ __launch_bounds__(512)
void head_kernel(const float* __restrict__ pooled, const float* __restrict__ Wd,
                 const float* __restrict__ bd, const int* __restrict__ ia,
                 const int* __restrict__ ib, float* __restrict__ out)
{
    __shared__ float og[G_SEG];
    const int g = threadIdx.x;
    if (g < G_SEG) {
        float acc = bd[0];
        #pragma unroll
        for (int i = 0; i < F_DIM; ++i) acc += pooled[(size_t)g * F_DIM + i] * Wd[i];
        og[g] = acc > 0.f ? acc : 0.f;
    }
    __syncthreads();
    for (int p = threadIdx.x; p < P_PAIRS; p += 512)
        out[p] = og[ib[p]] - og[ia[p]];
}

// ---------------------------------------------------------------------------
extern "C" void kernel_launch(void* const* d_in, const int* in_sizes, int n_in,
                              void* d_out, int out_size, void* d_ws, size_t ws_size,
                              hipStream_t stream)
{
    const float* x    = (const float*)d_in[0];
    const float* e    = (const float*)d_in[1];
    const int*   src  = (const int*)d_in[2];
    const int*   tgt  = (const int*)d_in[3];
    const int*   seg  = (const int*)d_in[4];
    const int*   ia   = (const int*)d_in[5];
    const int*   ib   = (const int*)d_in[6];
    const float* Wk1  = (const float*)d_in[7];
    const float* bk1  = (const float*)d_in[8];
    const float* root1= (const float*)d_in[9];
    const float* b1   = (const float*)d_in[10];
    const float* Wk2  = (const float*)d_in[11];
    const float* bk2  = (const float*)d_in[12];
    const float* root2= (const float*)d_in[13];
    const float* b2   = (const float*)d_in[14];
    const float* Wd   = (const float*)d_in[15];
    const float* bd   = (const float*)d_in[16];
    float* out = (float*)d_out;

    float* ag1    = (float*)d_ws;                       // 6.4 MB
    float* ag2    = ag1 + (size_t)N_NODES * F_DIM;      // 6.4 MB
    float* pooled = ag2 + (size_t)N_NODES * F_DIM;      // 64 KB
    float* esort  = pooled + (size_t)G_SEG * F_DIM;     // 6.4 MB
    float* msgbuf = esort + (size_t)N_EDGES * S_DIM;    // 25.6 MB
    int*   deg2     = (int*)(msgbuf + (size_t)N_EDGES * F_DIM);  // 2N
    int*   cursor   = deg2 + N2;                        // 2N
    int*   row      = cursor + N2;                      // 2N+1
    int*   partial  = row + (N2 + 1);                   // SCAN_B2
    int*   blockoff = partial + SCAN_B2;                // SCAN_B2
    int*   srcs     = blockoff + SCAN_B2;               // N_EDGES
    int*   postgt   = srcs + N_EDGES;                   // N_EDGES

    const int eblk = (N_EDGES + 255) / 256;
    const int fblk = (N_NODES + NB - 1) / NB;           // 3125
    const int iblk = (N_NODES * F_DIM + 255) / 256;
    const int rblk = (N_NODES + 7) / 8;                 // 6250

    zero_init     <<<SCAN_B2, 256, 0, stream>>>(deg2, pooled);
    deg_hist      <<<eblk, 256, 0, stream>>>(src, tgt, deg2);
    sum_blocks    <<<SCAN_B2, 256, 0, stream>>>(deg2, partial);
    scan_partials <<<1, 512, 0, stream>>>(partial, blockoff);
    write_rowstart<<<SCAN_B2, 256, 0, stream>>>(deg2, blockoff, row, cursor);
    csr_scatter   <<<eblk, 256, 0, stream>>>(src, tgt, e, cursor, srcs, postgt, esort);

    agg_init<0><<<iblk, 256, 0, stream>>>(x, root1, b1, ag1);
    fused_ecc<0><<<fblk, 320, 0, stream>>>(x, Wk1, bk1, row, srcs, postgt, esort, msgbuf);
    seg_reduce <<<rblk, 256, 0, stream>>>(msgbuf, row, ag1);

    agg_init<1><<<iblk, 256, 0, stream>>>(ag1, root2, b2, ag2);
    fused_ecc<1><<<fblk, 320, 0, stream>>>(ag1, Wk2, bk2, row, srcs, postgt, esort, msgbuf);
    seg_reduce <<<rblk, 256, 0, stream>>>(msgbuf, row, ag2);

    pool_kernel<<<SCAN_B, 256, 0, stream>>>(ag2, seg, pooled);
    head_kernel<<<1, 512, 0, stream>>>(pooled, Wd, bd, ia, ib, out);
}

// Round 8
// 192.576 us; speedup vs baseline: 1.2150x; 1.2150x over previous
//
#include <hip/hip_runtime.h>

#define N_NODES 50000
#define N_EDGES 200000
#define S_DIM   8
#define F_DIM   32      // F_IN == F == 32
#define G_SEG   512
#define P_PAIRS 1024
#define A_COLS  288     // 9*32 : 8 Wk rows + 1 bk row
#define NB      16      // source nodes per fused block
#define SCAN_B  196     // ceil(N_NODES/256)

// ---------------------------------------------------------------------------
// K0: zero deg[] and pooled[]
// ---------------------------------------------------------------------------
__global__ __launch_bounds__(256)
void zero_init(int* __restrict__ deg, float* __restrict__ pooled)
{
    const int gid = blockIdx.x * 256 + threadIdx.x;
    if (gid < N_NODES) deg[gid] = 0;
    if (gid < G_SEG * F_DIM) pooled[gid] = 0.f;
}

// CSR build: histogram of SOURCES
__global__ __launch_bounds__(256)
void deg_hist(const int* __restrict__ src, int* __restrict__ deg)
{
    const int e = blockIdx.x * 256 + threadIdx.x;
    if (e < N_EDGES) atomicAdd(&deg[src[e]], 1);
}

__global__ __launch_bounds__(256)
void sum_blocks(const int* __restrict__ deg, int* __restrict__ partial)
{
    __shared__ int sd[256];
    const int t = threadIdx.x;
    const int n = blockIdx.x * 256 + t;
    sd[t] = (n < N_NODES) ? deg[n] : 0;
    __syncthreads();
    for (int off = 128; off > 0; off >>= 1) {
        if (t < off) sd[t] += sd[t + off];
        __syncthreads();
    }
    if (t == 0) partial[blockIdx.x] = sd[0];
}

__global__ __launch_bounds__(256)
void scan_partials(const int* __restrict__ partial, int* __restrict__ blockoff)
{
    __shared__ int sd[256];
    const int t = threadIdx.x;
    sd[t] = (t < SCAN_B) ? partial[t] : 0;
    __syncthreads();
    for (int off = 1; off < 256; off <<= 1) {
        int v = (t >= off) ? sd[t - off] : 0;
        __syncthreads();
        sd[t] += v;
        __syncthreads();
    }
    if (t < SCAN_B) blockoff[t] = (t == 0) ? 0 : sd[t - 1];
}

__global__ __launch_bounds__(256)
void write_rowstart(const int* __restrict__ deg, const int* __restrict__ blockoff,
                    int* __restrict__ rowstart, int* __restrict__ cursor)
{
    __shared__ int sd[256];
    const int t = threadIdx.x;
    const int n = blockIdx.x * 256 + t;
    const int d = (n < N_NODES) ? deg[n] : 0;
    sd[t] = d;
    __syncthreads();
    for (int off = 1; off < 256; off <<= 1) {
        int v = (t >= off) ? sd[t - off] : 0;
        __syncthreads();
        sd[t] += v;
        __syncthreads();
    }
    if (n < N_NODES) {
        const int rs = blockoff[blockIdx.x] + sd[t] - d;
        rowstart[n] = rs;
        cursor[n]   = rs;
    }
    if (blockIdx.x == 0 && t == 0) rowstart[N_NODES] = N_EDGES;
}

// scatter edges into src-sorted order; pre-gather evec rows into esort
__global__ __launch_bounds__(256)
void csr_scatter(const int* __restrict__ src, const int* __restrict__ tgt,
                 const float* __restrict__ evec, int* __restrict__ cursor,
                 int* __restrict__ srcs, int* __restrict__ tgts,
                 float* __restrict__ esort)
{
    const int e = blockIdx.x * 256 + threadIdx.x;
    if (e < N_EDGES) {
        const int sn  = src[e];
        const int pos = atomicAdd(&cursor[sn], 1);
        srcs[pos] = sn;
        tgts[pos] = tgt[e];
        const float4* s4 = (const float4*)(evec + (size_t)e * S_DIM);
        float4* d4 = (float4*)(esort + (size_t)pos * S_DIM);
        d4[0] = s4[0];
        d4[1] = s4[1];
    }
}

// ---------------------------------------------------------------------------
// agg_init: agg[n][o] = b[o] + sum_i h[n][i] * root[i][o]
// ALSO writes hbuf[n][o] = h[n][o] (compact, relu'd) for fused_ecc's
// wave-uniform scalar reads.
// ---------------------------------------------------------------------------
template <int LAYER>
__global__ __launch_bounds__(256)
void agg_init(const float* __restrict__ hsrc, const float* __restrict__ root,
              const float* __restrict__ bias, float* __restrict__ agg,
              float* __restrict__ hbuf)
{
    __shared__ float r[F_DIM * F_DIM];
    __shared__ float bsh[F_DIM];
    for (int t = threadIdx.x; t < F_DIM * F_DIM; t += 256) r[t] = root[t];
    if (threadIdx.x < F_DIM) bsh[threadIdx.x] = bias[threadIdx.x];
    __syncthreads();

    const int gid = blockIdx.x * 256 + threadIdx.x;
    if (gid >= N_NODES * F_DIM) return;
    const int n = gid >> 5, o = gid & 31;

    // compact (and relu for layer 1) copy of this thread's own h element
    float own;
    if (LAYER == 0) own = hsrc[(size_t)n * (F_DIM + 1) + o];
    else {
        own = hsrc[(size_t)n * F_DIM + o];
        own = own > 0.f ? own : 0.f;
    }
    hbuf[(size_t)n * F_DIM + o] = own;

    float acc = bsh[o];
    #pragma unroll
    for (int i = 0; i < F_DIM; ++i) {
        float h;
        if (LAYER == 0) h = hsrc[(size_t)n * (F_DIM + 1) + i];
        else {
            h = hsrc[(size_t)n * F_DIM + i];
            h = h > 0.f ? h : 0.f;
        }
        acc += h * r[i * F_DIM + o];
    }
    agg[gid] = acc;
}

// ---------------------------------------------------------------------------
// fused_ecc: per block of NB=16 source nodes:
//   phase 1: A-tile[16][288] into LDS. h read via WAVE-UNIFORM loads from
//            hbuf (SGPR address -> s_load, scalar pipe; zero LDS reads).
//   phase 2: apply this block's src-sorted edges from LDS, atomicAdd to agg.
// LDS = 18KB (At only) -> 6 blocks/CU (wave-capped), no hh staging barrier.
// ---------------------------------------------------------------------------
__global__ __launch_bounds__(320)
void fused_ecc(const float* __restrict__ hbuf,
               const float* __restrict__ Wk, const float* __restrict__ bk,
               const int* __restrict__ rowstart, const int* __restrict__ srcs,
               const int* __restrict__ tgts, const float* __restrict__ esort,
               float* __restrict__ agg)
{
    __shared__ float At[NB][A_COLS];

    const int nb = blockIdx.x * NB;           // N_NODES % NB == 0 (3125 blocks)
    const int c  = threadIdx.x;

    if (c < A_COLS) {
        float w[F_DIM];
        const int o = c & 31;
        if (c < 256) {
            const int s = c >> 5;
            #pragma unroll
            for (int i = 0; i < F_DIM; ++i) w[i] = Wk[s * (F_DIM * F_DIM) + i * F_DIM + o];
        } else {
            #pragma unroll
            for (int i = 0; i < F_DIM; ++i) w[i] = bk[i * F_DIM + o];
        }
        // h rows read wave-uniformly (address depends only on nb, n, i4)
        const float4* h4 = (const float4*)(hbuf + (size_t)nb * F_DIM);
        #pragma unroll 4
        for (int n = 0; n < NB; ++n) {
            float acc = 0.f;
            #pragma unroll
            for (int i4 = 0; i4 < F_DIM / 4; ++i4) {
                const float4 hv = h4[n * (F_DIM / 4) + i4];   // uniform -> s_load
                acc += hv.x * w[4*i4]   + hv.y * w[4*i4+1]
                     + hv.z * w[4*i4+2] + hv.w * w[4*i4+3];
            }
            At[n][c] = acc;
        }
    }
    __syncthreads();

    const int r0 = rowstart[nb];
    const int r1 = rowstart[nb + NB];
    const int nwork = (r1 - r0) * F_DIM;
    for (int idx = threadIdx.x; idx < nwork; idx += 320) {
        const int pos = r0 + (idx >> 5);
        const int o   = idx & 31;
        const int ls  = srcs[pos] - nb;
        const int tn  = tgts[pos];
        const float4* ev4 = (const float4*)(esort + (size_t)pos * S_DIM);
        const float4 e0 = ev4[0];
        const float4 e1 = ev4[1];
        const float* Ar = At[ls];
        float m = Ar[8 * F_DIM + o];          // bk row (implicit e'_8 = 1)
        m += e0.x * Ar[0 * F_DIM + o];
        m += e0.y * Ar[1 * F_DIM + o];
        m += e0.z * Ar[2 * F_DIM + o];
        m += e0.w * Ar[3 * F_DIM + o];
        m += e1.x * Ar[4 * F_DIM + o];
        m += e1.y * Ar[5 * F_DIM + o];
        m += e1.z * Ar[6 * F_DIM + o];
        m += e1.w * Ar[7 * F_DIM + o];
        atomicAdd(&agg[(size_t)tn * F_DIM + o], m);
    }
}

// ---------------------------------------------------------------------------
// pool: pooled[seg[n]] += trunc(relu(agg2[n])). seg sorted -> run-based.
// ---------------------------------------------------------------------------
__global__ __launch_bounds__(256)
void pool_kernel(const float* __restrict__ agg2, const int* __restrict__ seg,
                 float* __restrict__ pooled)
{
    const int o    = threadIdx.x & 31;
    const int r    = threadIdx.x >> 5;
    const int base = blockIdx.x * 256 + r * 32;

    int   curseg = -1;
    float acc    = 0.f;
    for (int i = 0; i < 32; ++i) {
        const int n = base + i;
        if (n >= N_NODES) break;
        const int sg = seg[n];
        if (sg != curseg) {
            if (curseg >= 0 && acc != 0.f)
                atomicAdd(&pooled[(size_t)curseg * F_DIM + o], acc);
            curseg = sg;
            acc = 0.f;
        }
        float v = agg2[(size_t)n * F_DIM + o];
        v = v > 0.f ? v : 0.f;
        acc += truncf(v);
    }
    if (curseg >= 0 && acc != 0.f)
        atomicAdd(&pooled[(size_t)curseg * F_DIM + o], acc);
}

// ---------------------------------------------------------------------------
// head: out[g] = relu(pooled[g].Wd + bd); result[p] = out[ib[p]] - out[ia[p]]
// ---------------------------------------------------------------------------
__global__ __launch_bounds__(512)
void head_kernel(const float* __restrict__ pooled, const float* __restrict__ Wd,
                 const float* __restrict__ bd, const int* __restrict__ ia,
                 const int* __restrict__ ib, float* __restrict__ out)
{
    __shared__ float og[G_SEG];
    const int g = threadIdx.x;
    if (g < G_SEG) {
        float acc = bd[0];
        #pragma unroll
        for (int i = 0; i < F_DIM; ++i) acc += pooled[(size_t)g * F_DIM + i] * Wd[i];
        og[g] = acc > 0.f ? acc : 0.f;
    }
    __syncthreads();
    for (int p = threadIdx.x; p < P_PAIRS; p += 512)
        out[p] = og[ib[p]] - og[ia[p]];
}

// ---------------------------------------------------------------------------
extern "C" void kernel_launch(void* const* d_in, const int* in_sizes, int n_in,
                              void* d_out, int out_size, void* d_ws, size_t ws_size,
                              hipStream_t stream)
{
    const float* x    = (const float*)d_in[0];
    const float* e    = (const float*)d_in[1];
    const int*   src  = (const int*)d_in[2];
    const int*   tgt  = (const int*)d_in[3];
    const int*   seg  = (const int*)d_in[4];
    const int*   ia   = (const int*)d_in[5];
    const int*   ib   = (const int*)d_in[6];
    const float* Wk1  = (const float*)d_in[7];
    const float* bk1  = (const float*)d_in[8];
    const float* root1= (const float*)d_in[9];
    const float* b1   = (const float*)d_in[10];
    const float* Wk2  = (const float*)d_in[11];
    const float* bk2  = (const float*)d_in[12];
    const float* root2= (const float*)d_in[13];
    const float* b2   = (const float*)d_in[14];
    const float* Wd   = (const float*)d_in[15];
    const float* bd   = (const float*)d_in[16];
    float* out = (float*)d_out;

    float* ag1    = (float*)d_ws;                       // 6.4 MB
    float* ag2    = ag1 + (size_t)N_NODES * F_DIM;      // 6.4 MB
    float* pooled = ag2 + (size_t)N_NODES * F_DIM;      // 64 KB
    float* esort  = pooled + (size_t)G_SEG * F_DIM;     // 6.4 MB
    float* hbuf   = esort + (size_t)N_EDGES * S_DIM;    // 6.4 MB
    int*   deg      = (int*)(hbuf + (size_t)N_NODES * F_DIM);
    int*   cursor   = deg + N_NODES;
    int*   rowstart = cursor + N_NODES;                 // N_NODES+1
    int*   partial  = rowstart + (N_NODES + 1);
    int*   blockoff = partial + SCAN_B;
    int*   srcs     = blockoff + SCAN_B;                // N_EDGES
    int*   tgts     = srcs + N_EDGES;                   // N_EDGES

    const int eblk = (N_EDGES + 255) / 256;
    const int fblk = (N_NODES + NB - 1) / NB;           // 3125
    const int iblk = (N_NODES * F_DIM + 255) / 256;

    zero_init     <<<SCAN_B, 256, 0, stream>>>(deg, pooled);
    deg_hist      <<<eblk, 256, 0, stream>>>(src, deg);
    sum_blocks    <<<SCAN_B, 256, 0, stream>>>(deg, partial);
    scan_partials <<<1, 256, 0, stream>>>(partial, blockoff);
    write_rowstart<<<SCAN_B, 256, 0, stream>>>(deg, blockoff, rowstart, cursor);
    csr_scatter   <<<eblk, 256, 0, stream>>>(src, tgt, e, cursor, srcs, tgts, esort);

    agg_init<0><<<iblk, 256, 0, stream>>>(x,   root1, b1, ag1, hbuf);
    fused_ecc  <<<fblk, 320, 0, stream>>>(hbuf, Wk1, bk1, rowstart, srcs, tgts, esort, ag1);
    agg_init<1><<<iblk, 256, 0, stream>>>(ag1, root2, b2, ag2, hbuf);
    fused_ecc  <<<fblk, 320, 0, stream>>>(hbuf, Wk2, bk2, rowstart, srcs, tgts, esort, ag2);

    pool_kernel<<<SCAN_B, 256, 0, stream>>>(ag2, seg, pooled);
    head_kernel<<<1, 512, 0, stream>>>(pooled, Wd, bd, ia, ib, out);
}

// Round 9
// 177.533 us; speedup vs baseline: 1.3179x; 1.0847x over previous
//
#include <hip/hip_runtime.h>

#define N_NODES 50000
#define N_EDGES 200000
#define S_DIM   8
#define F_DIM   32      // F_IN == F == 32
#define G_SEG   512
#define P_PAIRS 1024
#define A_COLS  288     // 9*32 : 8 Wk rows + 1 bk row
#define NB      16      // source nodes per fused block
#define NGRP    3125    // N_NODES / NB
#define CAP     256     // bucket capacity (mean 64, sigma 8 -> never hit)
#define SCAN_B  196     // ceil(N_NODES/256)

// ---------------------------------------------------------------------------
// K0: zero bucket counters and pooled[]
// ---------------------------------------------------------------------------
__global__ __launch_bounds__(256)
void zero_init(int* __restrict__ cnt, float* __restrict__ pooled)
{
    const int gid = blockIdx.x * 256 + threadIdx.x;
    if (gid < NGRP) cnt[gid] = 0;
    if (gid < G_SEG * F_DIM) pooled[gid] = 0.f;
}

// ---------------------------------------------------------------------------
// K1: scatter edges into per-source-group buckets (no scan, no CSR).
//   meta = (ls << 16) | tgt   (ls = src & 15, tgt < 65536)
//   eS[g][pos][0..7] = evec row
// ---------------------------------------------------------------------------
__global__ __launch_bounds__(256)
void bucket_scatter(const int* __restrict__ src, const int* __restrict__ tgt,
                    const float* __restrict__ evec, int* __restrict__ cnt,
                    int* __restrict__ meta, float* __restrict__ eS)
{
    const int e = blockIdx.x * 256 + threadIdx.x;
    if (e >= N_EDGES) return;
    const int sn = src[e];
    const int g  = sn >> 4;
    const int ls = sn & (NB - 1);
    const int pos = atomicAdd(&cnt[g], 1);
    if (pos >= CAP) return;                       // statistically impossible
    meta[g * CAP + pos] = (ls << 16) | tgt[e];
    const float4* s4 = (const float4*)(evec + (size_t)e * S_DIM);
    float4* d4 = (float4*)(eS + ((size_t)g * CAP + pos) * S_DIM);
    d4[0] = s4[0];
    d4[1] = s4[1];
}

// ---------------------------------------------------------------------------
// agg_init: agg[n][o] = b[o] + sum_i h[n][i] * root[i][o]
// ALSO writes hbuf[n][o] (compact, relu'd for layer 1) for fused_ecc.
// ---------------------------------------------------------------------------
template <int LAYER>
__global__ __launch_bounds__(256)
void agg_init(const float* __restrict__ hsrc, const float* __restrict__ root,
              const float* __restrict__ bias, float* __restrict__ agg,
              float* __restrict__ hbuf)
{
    __shared__ float r[F_DIM * F_DIM];
    __shared__ float bsh[F_DIM];
    for (int t = threadIdx.x; t < F_DIM * F_DIM; t += 256) r[t] = root[t];
    if (threadIdx.x < F_DIM) bsh[threadIdx.x] = bias[threadIdx.x];
    __syncthreads();

    const int gid = blockIdx.x * 256 + threadIdx.x;
    if (gid >= N_NODES * F_DIM) return;
    const int n = gid >> 5, o = gid & 31;

    float own;
    if (LAYER == 0) own = hsrc[(size_t)n * (F_DIM + 1) + o];
    else {
        own = hsrc[(size_t)n * F_DIM + o];
        own = own > 0.f ? own : 0.f;
    }
    hbuf[(size_t)n * F_DIM + o] = own;

    float acc = bsh[o];
    #pragma unroll
    for (int i = 0; i < F_DIM; ++i) {
        float h;
        if (LAYER == 0) h = hsrc[(size_t)n * (F_DIM + 1) + i];
        else {
            h = hsrc[(size_t)n * F_DIM + i];
            h = h > 0.f ? h : 0.f;
        }
        acc += h * r[i * F_DIM + o];
    }
    agg[gid] = acc;
}

// ---------------------------------------------------------------------------
// fused_ecc, block g of NB=16 source nodes:
//   phase 1 (c < 288): A-tile[16][288] -> LDS; h via wave-uniform s_load.
//   phase 1 (c >= 288): 32 otherwise-idle threads stage meta -> LDS.
//   phase 2: msg per (edge,o) from LDS A + LDS meta + global eS (broadcast),
//            2x manual unroll, atomicAdd into agg.
// LDS = 18432 (At) + 1024 (meta) -> 6 blocks/CU (wave cap).
// ---------------------------------------------------------------------------
__global__ __launch_bounds__(320)
void fused_ecc(const float* __restrict__ hbuf,
               const float* __restrict__ Wk, const float* __restrict__ bk,
               const int* __restrict__ cntbuf, const int* __restrict__ meta,
               const float* __restrict__ eS, float* __restrict__ agg)
{
    __shared__ float At[NB][A_COLS];
    __shared__ int   smeta[CAP];

    const int g  = blockIdx.x;
    const int nb = g * NB;
    const int c  = threadIdx.x;
    const int cnt0 = cntbuf[g];
    const int cnt  = cnt0 < CAP ? cnt0 : CAP;

    if (c < A_COLS) {
        float w[F_DIM];
        const int o = c & 31;
        if (c < 256) {
            const int s = c >> 5;
            #pragma unroll
            for (int i = 0; i < F_DIM; ++i) w[i] = Wk[s * (F_DIM * F_DIM) + i * F_DIM + o];
        } else {
            #pragma unroll
            for (int i = 0; i < F_DIM; ++i) w[i] = bk[i * F_DIM + o];
        }
        const float4* h4 = (const float4*)(hbuf + (size_t)nb * F_DIM);
        #pragma unroll 4
        for (int n = 0; n < NB; ++n) {
            float acc = 0.f;
            #pragma unroll
            for (int i4 = 0; i4 < F_DIM / 4; ++i4) {
                const float4 hv = h4[n * (F_DIM / 4) + i4];   // uniform -> s_load
                acc += hv.x * w[4*i4]   + hv.y * w[4*i4+1]
                     + hv.z * w[4*i4+2] + hv.w * w[4*i4+3];
            }
            At[n][c] = acc;
        }
    } else {
        for (int i = c - A_COLS; i < cnt; i += 320 - A_COLS)
            smeta[i] = meta[g * CAP + i];
    }
    __syncthreads();

    const int nwork = cnt * F_DIM;
    const float* eSg = eS + (size_t)g * CAP * S_DIM;

    for (int base = 0; base < nwork; base += 640) {
        const int i0 = base + c;
        const int i1 = i0 + 320;
        const bool v1 = (i1 < nwork);
        if (i0 >= nwork) break;

        // ---- hoisted loads for both items (independent chains) ----
        const int p0 = i0 >> 5, o0 = i0 & 31;
        const int m0 = smeta[p0];
        const float4* ea0 = (const float4*)(eSg + (size_t)p0 * S_DIM);
        const float4 e00 = ea0[0], e01 = ea0[1];

        int p1 = 0, o1 = 0, m1 = 0;
        float4 e10, e11;
        if (v1) {
            p1 = i1 >> 5; o1 = i1 & 31;
            m1 = smeta[p1];
            const float4* ea1 = (const float4*)(eSg + (size_t)p1 * S_DIM);
            e10 = ea1[0]; e11 = ea1[1];
        }

        {
            const float* Ar = At[m0 >> 16];
            float m = Ar[8 * F_DIM + o0];
            m += e00.x * Ar[0 * F_DIM + o0];
            m += e00.y * Ar[1 * F_DIM + o0];
            m += e00.z * Ar[2 * F_DIM + o0];
            m += e00.w * Ar[3 * F_DIM + o0];
            m += e01.x * Ar[4 * F_DIM + o0];
            m += e01.y * Ar[5 * F_DIM + o0];
            m += e01.z * Ar[6 * F_DIM + o0];
            m += e01.w * Ar[7 * F_DIM + o0];
            atomicAdd(&agg[(size_t)(m0 & 0xFFFF) * F_DIM + o0], m);
        }
        if (v1) {
            const float* Ar = At[m1 >> 16];
            float m = Ar[8 * F_DIM + o1];
            m += e10.x * Ar[0 * F_DIM + o1];
            m += e10.y * Ar[1 * F_DIM + o1];
            m += e10.z * Ar[2 * F_DIM + o1];
            m += e10.w * Ar[3 * F_DIM + o1];
            m += e11.x * Ar[4 * F_DIM + o1];
            m += e11.y * Ar[5 * F_DIM + o1];
            m += e11.z * Ar[6 * F_DIM + o1];
            m += e11.w * Ar[7 * F_DIM + o1];
            atomicAdd(&agg[(size_t)(m1 & 0xFFFF) * F_DIM + o1], m);
        }
    }
}

// ---------------------------------------------------------------------------
// pool: pooled[seg[n]] += trunc(relu(agg2[n])). seg sorted -> run-based.
// ---------------------------------------------------------------------------
__global__ __launch_bounds__(256)
void pool_kernel(const float* __restrict__ agg2, const int* __restrict__ seg,
                 float* __restrict__ pooled)
{
    const int o    = threadIdx.x & 31;
    const int r    = threadIdx.x >> 5;
    const int base = blockIdx.x * 256 + r * 32;

    int   curseg = -1;
    float acc    = 0.f;
    for (int i = 0; i < 32; ++i) {
        const int n = base + i;
        if (n >= N_NODES) break;
        const int sg = seg[n];
        if (sg != curseg) {
            if (curseg >= 0 && acc != 0.f)
                atomicAdd(&pooled[(size_t)curseg * F_DIM + o], acc);
            curseg = sg;
            acc = 0.f;
        }
        float v = agg2[(size_t)n * F_DIM + o];
        v = v > 0.f ? v : 0.f;
        acc += truncf(v);
    }
    if (curseg >= 0 && acc != 0.f)
        atomicAdd(&pooled[(size_t)curseg * F_DIM + o], acc);
}

// ---------------------------------------------------------------------------
// head: out[g] = relu(pooled[g].Wd + bd); result[p] = out[ib[p]] - out[ia[p]]
// ---------------------------------------------------------------------------
__global__ __launch_bounds__(512)
void head_kernel(const float* __restrict__ pooled, const float* __restrict__ Wd,
                 const float* __restrict__ bd, const int* __restrict__ ia,
                 const int* __restrict__ ib, float* __restrict__ out)
{
    __shared__ float og[G_SEG];
    const int g = threadIdx.x;
    if (g < G_SEG) {
        float acc = bd[0];
        #pragma unroll
        for (int i = 0; i < F_DIM; ++i) acc += pooled[(size_t)g * F_DIM + i] * Wd[i];
        og[g] = acc > 0.f ? acc : 0.f;
    }
    __syncthreads();
    for (int p = threadIdx.x; p < P_PAIRS; p += 512)
        out[p] = og[ib[p]] - og[ia[p]];
}

// ---------------------------------------------------------------------------
extern "C" void kernel_launch(void* const* d_in, const int* in_sizes, int n_in,
                              void* d_out, int out_size, void* d_ws, size_t ws_size,
                              hipStream_t stream)
{
    const float* x    = (const float*)d_in[0];
    const float* e    = (const float*)d_in[1];
    const int*   src  = (const int*)d_in[2];
    const int*   tgt  = (const int*)d_in[3];
    const int*   seg  = (const int*)d_in[4];
    const int*   ia   = (const int*)d_in[5];
    const int*   ib   = (const int*)d_in[6];
    const float* Wk1  = (const float*)d_in[7];
    const float* bk1  = (const float*)d_in[8];
    const float* root1= (const float*)d_in[9];
    const float* b1   = (const float*)d_in[10];
    const float* Wk2  = (const float*)d_in[11];
    const float* bk2  = (const float*)d_in[12];
    const float* root2= (const float*)d_in[13];
    const float* b2   = (const float*)d_in[14];
    const float* Wd   = (const float*)d_in[15];
    const float* bd   = (const float*)d_in[16];
    float* out = (float*)d_out;

    float* ag1    = (float*)d_ws;                       // 6.4 MB
    float* ag2    = ag1 + (size_t)N_NODES * F_DIM;      // 6.4 MB
    float* pooled = ag2 + (size_t)N_NODES * F_DIM;      // 64 KB
    float* hbuf   = pooled + (size_t)G_SEG * F_DIM;     // 6.4 MB
    float* eS     = hbuf + (size_t)N_NODES * F_DIM;     // NGRP*CAP*8 f32 = 25.6 MB
    int*   meta   = (int*)(eS + (size_t)NGRP * CAP * S_DIM);   // 3.2 MB
    int*   cnt    = meta + (size_t)NGRP * CAP;          // 12.5 KB

    const int eblk = (N_EDGES + 255) / 256;
    const int iblk = (N_NODES * F_DIM + 255) / 256;

    zero_init     <<<64, 256, 0, stream>>>(cnt, pooled);
    bucket_scatter<<<eblk, 256, 0, stream>>>(src, tgt, e, cnt, meta, eS);

    agg_init<0><<<iblk, 256, 0, stream>>>(x,   root1, b1, ag1, hbuf);
    fused_ecc  <<<NGRP, 320, 0, stream>>>(hbuf, Wk1, bk1, cnt, meta, eS, ag1);
    agg_init<1><<<iblk, 256, 0, stream>>>(ag1, root2, b2, ag2, hbuf);
    fused_ecc  <<<NGRP, 320, 0, stream>>>(hbuf, Wk2, bk2, cnt, meta, eS, ag2);

    pool_kernel<<<SCAN_B, 256, 0, stream>>>(ag2, seg, pooled);
    head_kernel<<<1, 512, 0, stream>>>(pooled, Wd, bd, ia, ib, out);
}